// Round 2
// 293.914 us; speedup vs baseline: 1.0063x; 1.0063x over previous
//
#include <hip/hip_runtime.h>

typedef __attribute__((ext_vector_type(8))) short short8;
typedef __attribute__((ext_vector_type(4))) float float4v;

__device__ __forceinline__ float crelu(float v) {
    return fminf(1.0f, fmaxf(-1.0f, v));
}
// fp32 -> bf16 bits, round-to-nearest-even (finite inputs)
__device__ __forceinline__ uint f2bf_u(float v) {
    uint u = __float_as_uint(v);
    u += 0x7fffu + ((u >> 16) & 1u);
    return u >> 16;
}
__device__ __forceinline__ ushort f2bf(float v) { return (ushort)f2bf_u(v); }
__device__ __forceinline__ float bf2f_lo(uint u) { return __uint_as_float(u << 16); }
__device__ __forceinline__ float bf2f_hi(uint u) { return __uint_as_float(u & 0xffff0000u); }
// packed bf16 pair: lo = bf16(a), hi = bf16(b), RNE — 1 instr replaces ~8 VALU
__device__ __forceinline__ uint cvt_pk_bf16(float a, float b) {
    uint r;
    asm("v_cvt_pk_bf16_f32 %0, %1, %2" : "=v"(r) : "v"(a), "v"(b));
    return r;
}

#define ROW 385
#define BT  16            // samples per block = 4 waves x 4 samples

// per-wave LDS slab (bytes):
//   board: 4 samples x 544 ushort = 4352 B @ 0
//   hbuf : 144 tasks x 8 bf16     = 2304 B @ 4352
// aliases on dead board region after phase 1:
//   vis : f32[4][40]    @ 0     (640 B)
//   g1  : f32[4][20]    @ 640   (320 B)
//   E1T : f32[16][44]   @ 960   (2816 B)  stride 44: o*12 mod 32 -> conflict-free b128
//   E2T : bf16[16][16]  @ 3776  (512 B)
#define SLAB_BYTES 6656
#define E1T_OFF 960
#define E2T_OFF 3776
#define E1T_LD  44

__global__ __launch_bounds__(256, 6)
void lila_wave(const float* __restrict__ inp,
               const float* __restrict__ W1, const float* __restrict__ b1,
               const float* __restrict__ W2, const float* __restrict__ b2,
               const float* __restrict__ W3, const float* __restrict__ b3,
               const float* __restrict__ E1, const float* __restrict__ c1,
               const float* __restrict__ E2, const float* __restrict__ c2,
               const float* __restrict__ E3, const float* __restrict__ c3,
               float* __restrict__ out)
{
    __shared__ __align__(16) char slab_all[4 * SLAB_BYTES];   // 26624 B

    const int tid  = threadIdx.x;
    const int lane = tid & 63;
    const int wv   = tid >> 6;
    const int quad = lane >> 4;
    const int nn   = lane & 15;
    const int m0   = quad * 8;

    char*   slab  = slab_all + wv * SLAB_BYTES;
    ushort* board = (ushort*)slab;
    ushort* hbuf  = (ushort*)(slab + 4352);
    float*  vis   = (float*)slab;
    float*  g1    = (float*)(slab + 640);
    float*  e1t   = (float*)(slab + E1T_OFF);
    ushort* e2t   = (ushort*)(slab + E2T_OFF);

    const long long b0w = (long long)blockIdx.x * BT + wv * 4;

    // ---- B fragments for layer-1 MFMA, padded-cell K layout ----
    // k = quad*8 + j ; cell oy = k>>3, within-cell c = k&7.
    short8 bfr[3];
    #pragma unroll
    for (int r = 0; r < 3; ++r) {
        #pragma unroll
        for (int j = 0; j < 8; ++j) {
            int k = m0 + j, oy = k >> 3, c = k & 7;
            float w = (oy < 3 && c < 6 && nn < 8)
                    ? W1[(r * 18 + oy * 6 + c) * 8 + nn] : 0.0f;
            bfr[r][j] = (short)f2bf(w);
        }
    }
    const float bias1 = (nn < 8) ? b1[nn] : 0.0f;

    // ---- stage 4 samples -> padded bf16 board, 16B writes ----
    const int r   = lane >> 4;          // sample within wave
    const int c16 = lane & 15;
    const float* gr = inp + (b0w + r) * ROW;

    if (c16 < 4) {
        uint4 z = {0u, 0u, 0u, 0u};
        *(uint4*)(board + r * 544 + 512 + c16 * 8) = z;
    }
    #pragma unroll
    for (int u = 0; u < 4; ++u) {
        int cell = c16 + 16 * u;
        int g = cell * 6;
        float4 q0 = *(const float4*)(gr + g);       // dword-aligned, HW handles
        float2 q1 = *(const float2*)(gr + g + 4);
        uint4 pk;
        pk.x = cvt_pk_bf16(q0.x, q0.y);
        pk.y = cvt_pk_bf16(q0.z, q0.w);
        pk.z = cvt_pk_bf16(q1.x, q1.y);
        pk.w = 0u;
        *(uint4*)(board + r * 544 + cell * 8) = pk;
    }
    const float cen = gr[384];

    asm volatile("" ::: "memory");   // staging writes before phase-1 reads

    // ---- phase 1: layer 1 (54->8) via bf16 MFMA ----
    #pragma unroll 3
    for (int t = 0; t < 9; ++t) {
        int ltask = t * 16 + nn;
        uint lb = (uint)ltask / 36u;
        uint p  = (uint)ltask - 36u * lb;
        uint x  = p / 6u;
        uint y  = p - 6u * x;
        const ushort* base = board + lb * 544 + x * 64 + 8 * y + m0;
        union { uint4 u; short8 s; } a0, a1, a2;
        a0.u = *(const uint4*)(base);
        a1.u = *(const uint4*)(base + 64);
        a2.u = *(const uint4*)(base + 128);
        float4v acc = { bias1, bias1, bias1, bias1 };
        acc = __builtin_amdgcn_mfma_f32_16x16x32_bf16(a0.s, bfr[0], acc, 0, 0, 0);
        acc = __builtin_amdgcn_mfma_f32_16x16x32_bf16(a1.s, bfr[1], acc, 0, 0, 0);
        acc = __builtin_amdgcn_mfma_f32_16x16x32_bf16(a2.s, bfr[2], acc, 0, 0, 0);
        if (nn < 8) {
            uint w01 = cvt_pk_bf16(crelu(acc[0]), crelu(acc[1]));
            uint w23 = cvt_pk_bf16(crelu(acc[2]), crelu(acc[3]));
            ushort* hb = hbuf + (t * 16 + quad * 4) * 8 + nn;
            hb[0]  = (ushort)w01;
            hb[8]  = (ushort)(w01 >> 16);
            hb[16] = (ushort)w23;
            hb[24] = (ushort)(w23 >> 16);
        }
    }

    asm volatile("" ::: "memory");   // phase-1 board reads done; board now dead

    // ---- E-stage: wave-private E1T (f32, stride 44) + E2T (bf16) ----
    // E1 flat j = lane + 64k -> f = r + 4k, o = nn  (j < 592)
    {
        float e1g[10];
        #pragma unroll
        for (int k = 0; k < 9; ++k) e1g[k] = E1[lane + 64 * k];
        if (lane < 16) e1g[9] = E1[lane + 576];
        float e2g[4];
        #pragma unroll
        for (int k = 0; k < 4; ++k) e2g[k] = E2[lane + 64 * k];

        #pragma unroll
        for (int k = 0; k < 9; ++k) e1t[nn * E1T_LD + r + 4 * k] = e1g[k];
        if (lane < 16) e1t[nn * E1T_LD + 36] = e1g[9];
        #pragma unroll
        for (int k = 0; k < 4; ++k) e2t[nn * 16 + r + 4 * k] = f2bf(e2g[k]);
    }
    const float c1v = c1[nn];
    const float c2v = c2[nn];
    const float e3v = E3[nn];

    asm volatile("" ::: "memory");

    // ---- phase 2: layers 2 (8->8) + 3 (8->1) via MFMA, 2 tasks per row ----
    // A row = task within 16-group; K slots 0-7 = group A (tasks 0..79),
    // slots 8-15 = group B (tasks 80..143). B = W2 block-replicated
    // (cols 0-7 <- k 0-7, cols 8-15 <- k 8-15), split into bf16 hi + bf16
    // residual so layer-2 numerics stay ~fp32.
    {
        short8 w2fh, w2fl;
        const int colq = nn - quad * 8;        // valid W2 col iff quad<2 && 0<=colq<8
        #pragma unroll
        for (int j = 0; j < 8; ++j) {
            float w = (quad < 2 && colq >= 0 && colq < 8) ? W2[j * 8 + colq] : 0.0f;
            uint hb = f2bf_u(w);
            float wr = w - __uint_as_float(hb << 16);
            w2fh[j] = (short)hb;
            w2fl[j] = (short)f2bf(wr);
        }
        const float b2v = b2[nn & 7];
        const float w3v = W3[nn & 7];
        const float b3v = b3[0];

        #pragma unroll
        for (int t = 0; t < 5; ++t) {          // A: t=0..4 (80 tasks), B: t=0..3 (64 tasks)
            union { uint4 u; short8 s; } av;
            av.u.x = 0u; av.u.y = 0u; av.u.z = 0u; av.u.w = 0u;
            int tsk = t * 16 + nn + (quad ? 80 : 0);
            if (quad < 2 && (t < 4 || quad == 0))
                av.u = *(const uint4*)(hbuf + tsk * 8);
            float4v acc = { b2v, b2v, b2v, b2v };
            acc = __builtin_amdgcn_mfma_f32_16x16x32_bf16(av.s, w2fh, acc, 0, 0, 0);
            acc = __builtin_amdgcn_mfma_f32_16x16x32_bf16(av.s, w2fl, acc, 0, 0, 0);
            // layer 3: dot over o (8 lanes of this o-group), then crelu + store
            float vsum[4];
            #pragma unroll
            for (int i = 0; i < 4; ++i) {
                float vv = crelu(acc[i]) * w3v;
                vv += __shfl_xor(vv, 1);
                vv += __shfl_xor(vv, 2);
                vv += __shfl_xor(vv, 4);
                vsum[i] = vv;
            }
            const bool isA = (nn == 0);
            if ((nn & 7) == 0 && (isA || t < 4)) {
                int task = (isA ? 0 : 80) + t * 16 + quad * 4;   // 4-aligned, same lb
                uint lb = (uint)task / 36u;
                uint p  = (uint)task - 36u * lb;
                float4 o4;
                o4.x = crelu(vsum[0] + b3v);
                o4.y = crelu(vsum[1] + b3v);
                o4.z = crelu(vsum[2] + b3v);
                o4.w = crelu(vsum[3] + b3v);
                *(float4*)(vis + lb * 40 + p) = o4;
            }
        }
    }

    asm volatile("" ::: "memory");   // vis + E-tables written before phase-3 reads

    // ---- phase 3: vision head 37->16->16->1 ; lane = (sample r, output nn) ----
    {
        const int o = nn;
        float a = c1v;
        #pragma unroll
        for (int fi = 0; fi < 9; ++fi) {
            float4 vv = *(const float4*)(vis + r * 40 + fi * 4);
            float4 ev = *(const float4*)(e1t + o * E1T_LD + fi * 4);
            a = fmaf(vv.x, ev.x, a);
            a = fmaf(vv.y, ev.y, a);
            a = fmaf(vv.z, ev.z, a);
            a = fmaf(vv.w, ev.w, a);
        }
        a = fmaf(cen, e1t[o * E1T_LD + 36], a);
        g1[r * 20 + o] = crelu(a);

        asm volatile("" ::: "memory");

        uint4 e2a = *(const uint4*)(e2t + o * 16);      // 16 bf16 weights
        uint4 e2b = *(const uint4*)(e2t + o * 16 + 8);
        float a2 = c2v;
        #pragma unroll
        for (int fi = 0; fi < 4; ++fi) {
            float4 gv = *(const float4*)(g1 + r * 20 + fi * 4);
            uint w01 = (fi < 2) ? (fi == 0 ? e2a.x : e2a.z) : (fi == 2 ? e2b.x : e2b.z);
            uint w23 = (fi < 2) ? (fi == 0 ? e2a.y : e2a.w) : (fi == 2 ? e2b.y : e2b.w);
            a2 = fmaf(gv.x, bf2f_lo(w01), a2);
            a2 = fmaf(gv.y, bf2f_hi(w01), a2);
            a2 = fmaf(gv.z, bf2f_lo(w23), a2);
            a2 = fmaf(gv.w, bf2f_hi(w23), a2);
        }
        float tv = crelu(a2) * e3v;
        tv += __shfl_xor(tv, 1);
        tv += __shfl_xor(tv, 2);
        tv += __shfl_xor(tv, 4);
        tv += __shfl_xor(tv, 8);
        if (o == 0) out[b0w + r] = crelu(tv + c3[0]);
    }
}

extern "C" void kernel_launch(void* const* d_in, const int* in_sizes, int n_in,
                              void* d_out, int out_size, void* d_ws, size_t ws_size,
                              hipStream_t stream)
{
    const float* inp = (const float*)d_in[0];
    const float* W1  = (const float*)d_in[1];
    const float* b1  = (const float*)d_in[2];
    const float* W2  = (const float*)d_in[3];
    const float* b2  = (const float*)d_in[4];
    const float* W3  = (const float*)d_in[5];
    const float* b3  = (const float*)d_in[6];
    const float* E1  = (const float*)d_in[7];
    const float* c1  = (const float*)d_in[8];
    const float* E2  = (const float*)d_in[9];
    const float* c2  = (const float*)d_in[10];
    const float* E3  = (const float*)d_in[11];
    const float* c3  = (const float*)d_in[12];
    float* out = (float*)d_out;

    int B = in_sizes[0] / ROW;           // 131072
    int grid = B / BT;                   // 8192 blocks
    lila_wave<<<grid, 256, 0, stream>>>(inp, W1, b1, W2, b2, W3, b3,
                                        E1, c1, E2, c2, E3, c3, out);
}